// Round 15
// baseline (157.374 us; speedup 1.0000x reference)
//
#include <hip/hip_runtime.h>
#include <hip/hip_bf16.h>
#include <math.h>

using bf16 = __hip_bfloat16;
typedef __attribute__((ext_vector_type(8))) short bf16x8;
typedef __attribute__((ext_vector_type(4))) float f32x4;
typedef __attribute__((ext_vector_type(4))) unsigned short us4;

#define GAS __attribute__((address_space(1)))
#define LAS __attribute__((address_space(3)))

__device__ __forceinline__ void gload_lds16(const bf16* g, bf16* lds) {
  __builtin_amdgcn_global_load_lds((const GAS void*)g, (LAS void*)lds, 16, 0, 0);
}
__device__ __forceinline__ float b2f(unsigned short u) {
  union { unsigned short s; bf16 b; } x; x.s = u; return __bfloat162float(x.b);
}

// ---------------- compaction (atomic-free, stable => deterministic) ----------------
__global__ __launch_bounds__(256) void hist_k(const int* __restrict__ lab,
                                              int* __restrict__ blockHist) {
  const int blk = blockIdx.x, t = threadIdx.x;
  const int lane = t & 63, w = t >> 6;
  const int d = lab[blk * 256 + t];
  __shared__ int wc[4][3];
#pragma unroll
  for (int dd = 0; dd < 3; ++dd) {
    unsigned long long m = __ballot(d == dd);
    if (lane == 0) wc[w][dd] = __popcll(m);
  }
  __syncthreads();
  if (t < 3) blockHist[blk * 3 + t] = wc[0][t] + wc[1][t] + wc[2][t] + wc[3][t];
}

__global__ __launch_bounds__(256) void scan_k(const int* __restrict__ blockHist,
                                              int* __restrict__ blockOff,
                                              int* __restrict__ meta) {
  __shared__ int h[64][3];
  __shared__ int tot[3];
  const int t = threadIdx.x;
  if (t < 192) h[t / 3][t % 3] = blockHist[t];
  __syncthreads();
  if (t < 3) {
    int s = 0;
    for (int b = 0; b < 64; ++b) { int v = h[b][t]; h[b][t] = s; s += v; }
    tot[t] = s;
    meta[t] = s;
  }
  __syncthreads();
  if (t == 0) { meta[4] = 0; meta[5] = tot[0]; meta[6] = tot[0] + tot[1]; }
  if (t < 192) {
    int b = t / 3, d = t % 3;
    int base = (d == 0) ? 0 : (d == 1 ? tot[0] : tot[0] + tot[1]);
    blockOff[t] = base + h[b][d];
  }
}

__global__ __launch_bounds__(256) void scatter2_k(const int* __restrict__ lab,
                                                  const int* __restrict__ blockOff,
                                                  int* __restrict__ perm,
                                                  int* __restrict__ iperm) {
  const int blk = blockIdx.x, t = threadIdx.x;
  const int lane = t & 63, w = t >> 6;
  const int i = blk * 256 + t;
  const int d = lab[i];
  __shared__ int wc[4][3];
  unsigned long long mymask = 0;
#pragma unroll
  for (int dd = 0; dd < 3; ++dd) {
    unsigned long long m = __ballot(d == dd);
    if (lane == 0) wc[w][dd] = __popcll(m);
    if (dd == d) mymask = m;
  }
  __syncthreads();
  int woff = 0;
  for (int ww = 0; ww < w; ++ww) woff += wc[ww][d];
  const unsigned long long lt = ((unsigned long long)1 << lane) - 1;
  const int rank = blockOff[blk * 3 + d] + woff + __popcll(mymask & lt);
  perm[rank] = i;
  iperm[i] = rank;
}

// ------- merged prep: blocks 0..383 = LDS-tiled W1/W2 transpose+cvt; rest = cvt -------
__global__ __launch_bounds__(256) void prep_k(const float* __restrict__ x,
                                              const float* __restrict__ txt,
                                              const float* __restrict__ W1,
                                              const float* __restrict__ W2,
                                              const int* __restrict__ iperm,
                                              bf16* __restrict__ Xbc,
                                              bf16* __restrict__ Tb,
                                              bf16* __restrict__ W1T,
                                              bf16* __restrict__ W2T) {
  __shared__ float s[64][65];
  if (blockIdx.x < 384) {
    int b = blockIdx.x;
    const float* W; bf16* WT; int R, C;
    if (b < 192) { W = W1; WT = W1T; R = 1024; C = 256; }
    else         { b -= 192; W = W2; WT = W2T; R = 256; C = 1024; }
    const int d = b / 64, tb = b % 64;
    const int tilesPerRow = C / 64;
    const int r0 = (tb / tilesPerRow) * 64;
    const int c0 = (tb % tilesPerRow) * 64;
    const float* Wd = W + (size_t)d * R * C;
    bf16* WTd = WT + (size_t)d * R * C;
    const int tx = threadIdx.x & 63, ty = threadIdx.x >> 6;
#pragma unroll
    for (int i = 0; i < 16; ++i)
      s[ty + i * 4][tx] = Wd[(size_t)(r0 + ty + i * 4) * C + c0 + tx];
    __syncthreads();
#pragma unroll
    for (int i = 0; i < 16; ++i)
      WTd[(size_t)(c0 + ty + i * 4) * R + r0 + tx] = __float2bfloat16(s[tx][ty + i * 4]);
    return;
  }
  const int nx = 16384 * 1024 / 4;
  const int ntext = 1536 * 1024;
  const int total = nx + ntext;
  for (int i = (blockIdx.x - 384) * 256 + threadIdx.x; i < total; i += 2048 * 256) {
    if (i < nx) {
      const int row = i >> 8, c4 = i & 255;
      float4 v = ((const float4*)x)[i];
      bf16 t[4] = {__float2bfloat16(v.x), __float2bfloat16(v.y),
                   __float2bfloat16(v.z), __float2bfloat16(v.w)};
      ((us4*)Xbc)[(size_t)iperm[row] * 256 + c4] = *(const us4*)t;
    } else {
      int jj = i - nx;
      Tb[jj] = (jj < 1380 * 1024) ? __float2bfloat16(txt[jj]) : __float2bfloat16(0.f);
    }
  }
}

// -------- 128^2 2-phase GEMM for GEMM1/GEMM2 — dense compacted rows, BK templated --------
template <int EPI, int NBLK, int BK>
__global__ __launch_bounds__(256) void gemm_bt(
    const bf16* __restrict__ A, const bf16* __restrict__ BT, bf16* __restrict__ Cv,
    const int* __restrict__ meta, int N, int K, int ldc, int Nvalid,
    const bf16* __restrict__ xb, float* __restrict__ ssp) {
  const int bid = blockIdx.x;
  const int xcd = bid & 7;
  const int seq = bid >> 3;
  const int nblkidx = seq % NBLK;
  const int dm = xcd + 8 * (seq / NBLK);
  const int dom = dm >> 7;
  const int mblk = dm & 127;

  const int cnt = meta[dom];
  const int base = meta[4 + dom];
  BT += (size_t)dom * N * K;

  const int m0 = mblk * 128;
  if (m0 >= cnt) return;
  const int n0 = nblkidx * 128;

  constexpr int CH = BK / 8;
  __shared__ bf16 sA[2][128][BK];
  __shared__ bf16 sB[2][128][BK];

  const int tid = threadIdx.x;
  const int wid = tid >> 6;
  const int lane = tid & 63;
  const int fr = lane & 15;
  const int fq = lane >> 4;

  auto stage = [&](int buf, int kt) {
    const int koff = kt * BK;
#pragma unroll
    for (int L = 0; L < CH / 2; ++L) {
      const int idx = L * 256 + tid;
      const int r = idx / CH, c = idx % CH;
      int ar = m0 + r; if (ar > cnt - 1) ar = cnt - 1;
      gload_lds16(A + (size_t)(base + ar) * K + koff + ((c ^ (r & (CH - 1))) << 3),
                  &sA[buf][0][0] + ((idx & ~63) << 3));
    }
#pragma unroll
    for (int L = 0; L < CH / 2; ++L) {
      const int idx = L * 256 + tid;
      const int r = idx / CH, c = idx % CH;
      gload_lds16(BT + (size_t)(n0 + r) * K + koff + ((c ^ (r & (CH - 1))) << 3),
                  &sB[buf][0][0] + ((idx & ~63) << 3));
    }
  };

  f32x4 acc[4][4];
#pragma unroll
  for (int m = 0; m < 4; ++m)
#pragma unroll
    for (int n = 0; n < 4; ++n) acc[m][n] = (f32x4){0.f, 0.f, 0.f, 0.f};

  const int nk = K / BK;
  stage(0, 0);
  __syncthreads();
  const int wr = wid >> 1, wc = wid & 1;
  for (int kt = 0; kt < nk; ++kt) {
    const int cur = kt & 1;
    if (kt + 1 < nk) stage(cur ^ 1, kt + 1);
#pragma unroll
    for (int kk = 0; kk < BK / 32; ++kk) {
      const int rchunk = (((kk << 2) + fq) ^ (fr & (CH - 1))) << 3;
      bf16x8 af[4], bfr[4];
#pragma unroll
      for (int m = 0; m < 4; ++m)
        af[m] = *(const bf16x8*)&sA[cur][wr * 64 + m * 16 + fr][0 + rchunk];
#pragma unroll
      for (int n = 0; n < 4; ++n)
        bfr[n] = *(const bf16x8*)&sB[cur][wc * 64 + n * 16 + fr][0 + rchunk];
#pragma unroll
      for (int m = 0; m < 4; ++m)
#pragma unroll
        for (int n = 0; n < 4; ++n)
          acc[m][n] = __builtin_amdgcn_mfma_f32_16x16x32_bf16(af[m], bfr[n], acc[m][n], 0, 0, 0);
    }
    __syncthreads();
  }

  if (EPI == 0) {
#pragma unroll
    for (int m = 0; m < 4; ++m) {
#pragma unroll
      for (int r = 0; r < 4; ++r) {
        const int p = m0 + wr * 64 + m * 16 + fq * 4 + r;
        if (p < cnt) {
          const size_t crow = (size_t)(base + p);
#pragma unroll
          for (int n = 0; n < 4; ++n) {
            const int col = n0 + wc * 64 + n * 16 + fr;
            if (col < Nvalid)
              Cv[crow * (size_t)ldc + col] = __float2bfloat16(fmaxf(acc[m][n][r], 0.f));
          }
        }
      }
    }
  } else {
    __shared__ float ssred[128][2];
#pragma unroll
    for (int m = 0; m < 4; ++m) {
#pragma unroll
      for (int r = 0; r < 4; ++r) {
        const int lr = wr * 64 + m * 16 + fq * 4 + r;
        const int p = m0 + lr;
        float rowss = 0.f;
        if (p < cnt) {
          const size_t crow = (size_t)(base + p);
#pragma unroll
          for (int n = 0; n < 4; ++n) {
            const int col = n0 + wc * 64 + n * 16 + fr;
            const float g = 0.2f * fmaxf(acc[m][n][r], 0.f) +
                            0.8f * b2f(*(const unsigned short*)&xb[crow * 1024 + col]);
            Cv[crow * (size_t)ldc + col] = __float2bfloat16(g);
            rowss += g * g;
          }
        }
        rowss += __shfl_xor(rowss, 1, 16);
        rowss += __shfl_xor(rowss, 2, 16);
        rowss += __shfl_xor(rowss, 4, 16);
        rowss += __shfl_xor(rowss, 8, 16);
        if (fr == 0) ssred[lr][wc] = rowss;
      }
    }
    __syncthreads();
    if (tid < 128) {
      const int p = m0 + tid;
      if (p < cnt)
        ssp[(size_t)nblkidx * 16384 + base + p] = ssred[tid][0] + ssred[tid][1];
    }
  }
}

// ====== GEMM3: 256x192, BK=64, 8 waves, 112KB LDS, 4 fine phases/K-tile ======
// Grid 64x8=512 = 2 packed rounds. Per tile t (slot s=t&1), phases:
//  p0: 11 ds_read (A kk0 x8 + B kk0 x3) | lgk0 | bar | 12 MFMA (kk0,m0-3)
//  p1: 11 ds_read (A kk1 x8 + B kk1 x3) | lgk0 | bar | 12 MFMA (kk0,m4-7)
//      ^ after p1's bar, ALL slot-s LDS reads are complete
//  p2: STAGE_A(t+2 -> slot s) 4 sweeps  | bar | 12 MFMA (kk1,m0-3)
//  p3: STAGE_B(t+2) 3 sweeps | bar | 12 MFMA (kk1,m4-7) | vmcnt(7) | bar
// Uniform 7 loads/thread/tile => vmcnt(7) drains exactly tile t+1 (FIFO), never young.
// Same K-order & fragment mapping as before => bit-identical output.
__global__ __launch_bounds__(512, 2) void gemm3_8ph(
    const bf16* __restrict__ A, const bf16* __restrict__ BT,
    float* __restrict__ C, const float* __restrict__ scale_ptr,
    const float* __restrict__ ssp, const int* __restrict__ perm) {
  extern __shared__ bf16 smem[];
  bf16* sA0 = smem;            // [2][256][64] = 64KB
  bf16* sB0 = smem + 32768;    // [2][192][64] = 48KB

  const int tid = threadIdx.x;
  const int lane = tid & 63, wid = tid >> 6;
  const int wr = wid >> 2, wc = wid & 3;     // 2x4; wave C = 128 x 48
  const int fr = lane & 15, fq = lane >> 4;

  const int bid = blockIdx.x;
  const int x = bid & 7, seq = bid >> 3;     // seq 0..63
  const int mb = x * 8 + (seq >> 3), nb = seq & 7;
  const int m0 = mb << 8, n0 = nb * 192;

  auto STAGE_A = [&](int t) {    // 4 sweeps x 1 load/thread
    const int s = t & 1, koff = t << 6;
    bf16* da = sA0 + (s << 14);
#pragma unroll
    for (int L = 0; L < 4; ++L) {
      const int idx = (L << 9) + tid;
      const int r = idx >> 3, c = idx & 7;
      gload_lds16(A + (size_t)(m0 + r) * 1024 + koff + ((c ^ (r & 7)) << 3),
                  da + ((idx & ~63) << 3));
    }
  };
  auto STAGE_B = [&](int t) {    // 3 sweeps x 1 load/thread
    const int s = t & 1, koff = t << 6;
    bf16* db = sB0 + s * 12288;
#pragma unroll
    for (int L = 0; L < 3; ++L) {
      const int idx = (L << 9) + tid;
      const int r = idx >> 3, c = idx & 7;
      gload_lds16(BT + (size_t)(n0 + r) * 1024 + koff + ((c ^ (r & 7)) << 3),
                  db + ((idx & ~63) << 3));
    }
  };
  auto LDA4 = [&](int s, int kk, int mh, bf16x8* dst) {   // 4 A-frags (half the m's)
    const bf16* base = sA0 + (s << 14);
#pragma unroll
    for (int m = 0; m < 4; ++m) {
      const int row = (wr << 7) + (mh << 6) + (m << 4) + fr;
      dst[m] = *(const bf16x8*)(base + (row << 6) + ((((kk << 2) + fq) ^ (fr & 7)) << 3));
    }
  };
  auto LDB3 = [&](int s, int kk, bf16x8* dst) {
    const bf16* base = sB0 + s * 12288;
#pragma unroll
    for (int n = 0; n < 3; ++n) {
      const int row = wc * 48 + (n << 4) + fr;
      dst[n] = *(const bf16x8*)(base + (row << 6) + ((((kk << 2) + fq) ^ (fr & 7)) << 3));
    }
  };

  f32x4 acc[8][3];
#pragma unroll
  for (int m = 0; m < 8; ++m)
#pragma unroll
    for (int n = 0; n < 3; ++n) acc[m][n] = (f32x4){0.f, 0.f, 0.f, 0.f};

#define SB __builtin_amdgcn_sched_barrier(0)
#define BAR __builtin_amdgcn_s_barrier()
#define MM12(AF, BF, MB)                                                          \
  _Pragma("unroll") for (int m = 0; m < 4; ++m) {                                 \
    _Pragma("unroll") for (int n = 0; n < 3; ++n) {                               \
      acc[MB + m][n] = __builtin_amdgcn_mfma_f32_16x16x32_bf16(                   \
          AF[m], BF[n], acc[MB + m][n], 0, 0, 0);                                 \
    }                                                                             \
  }

  // prologue: tiles 0,1 fully staged (7 loads each); drain tile0, keep tile1 flying
  STAGE_A(0); STAGE_B(0); STAGE_A(1); STAGE_B(1);
  asm volatile("s_waitcnt vmcnt(7)" ::: "memory");
  SB; BAR; SB;

  const int nt = 16;
  for (int t = 0; t < nt; ++t) {
    const int s = t & 1;
    bf16x8 a0l[4], a0h[4], a1l[4], a1h[4], b0[3], b1[3];
    // ---- p0: read kk0 frags; MFMA kk0 m0-3
    LDA4(s, 0, 0, a0l); LDA4(s, 0, 1, a0h); LDB3(s, 0, b0);
    asm volatile("s_waitcnt lgkmcnt(0)" ::: "memory");
    SB; BAR; SB;
    __builtin_amdgcn_s_setprio(1);
    MM12(a0l, b0, 0);
    __builtin_amdgcn_s_setprio(0);
    // ---- p1: read kk1 frags; MFMA kk0 m4-7
    LDA4(s, 1, 0, a1l); LDA4(s, 1, 1, a1h); LDB3(s, 1, b1);
    asm volatile("s_waitcnt lgkmcnt(0)" ::: "memory");
    SB; BAR; SB;                       // after this: ALL slot-s reads complete
    __builtin_amdgcn_s_setprio(1);
    MM12(a0h, b0, 4);
    __builtin_amdgcn_s_setprio(0);
    // ---- p2: stage A(t+2) into slot s; MFMA kk1 m0-3
    if (t + 2 < nt) STAGE_A(t + 2);
    SB; BAR; SB;
    __builtin_amdgcn_s_setprio(1);
    MM12(a1l, b1, 0);
    __builtin_amdgcn_s_setprio(0);
    // ---- p3: stage B(t+2); MFMA kk1 m4-7; counted drain of t+1
    if (t + 2 < nt) STAGE_B(t + 2);
    SB; BAR; SB;
    __builtin_amdgcn_s_setprio(1);
    MM12(a1h, b1, 4);
    __builtin_amdgcn_s_setprio(0);
    if (t + 2 < nt) {
      asm volatile("s_waitcnt vmcnt(7)" ::: "memory");
    } else if (t + 1 < nt) {
      asm volatile("s_waitcnt vmcnt(0)" ::: "memory");
    }
    SB; BAR; SB;
  }
#undef MM12
#undef BAR
#undef SB

  // in-kernel rinv + perm for this block's 256 rows
  float* rlds = (float*)smem;                        // 1KB
  int*   plds = (int*)((char*)smem + 1024);          // 1KB
  if (tid < 256) {
    float s = 0.f;
#pragma unroll
    for (int b = 0; b < 8; ++b) s += ssp[b * 16384 + m0 + tid];
    rlds[tid] = rsqrtf(s);
    plds[tid] = perm[m0 + tid];
  }
  __syncthreads();

  const float sc = expf(*scale_ptr);
#pragma unroll
  for (int m = 0; m < 8; ++m) {
    const int lrow = (wr << 7) + (m << 4) + (fq << 2);
#pragma unroll
    for (int r = 0; r < 4; ++r) {
      const float rv = sc * rlds[lrow + r];
      const size_t orow = (size_t)plds[lrow + r];
#pragma unroll
      for (int n = 0; n < 3; ++n) {
        const int gcol = n0 + wc * 48 + (n << 4) + fr;
        if (gcol < 1380) C[orow * 1380 + gcol] = acc[m][n][r] * rv;
      }
    }
  }
}

extern "C" void kernel_launch(void* const* d_in, const int* in_sizes, int n_in,
                              void* d_out, int out_size, void* d_ws, size_t ws_size,
                              hipStream_t stream) {
  (void)in_sizes; (void)n_in; (void)out_size; (void)ws_size;
  const float* x    = (const float*)d_in[0];
  const int*   lab  = (const int*)d_in[1];
  const float* W1   = (const float*)d_in[2];
  const float* W2   = (const float*)d_in[3];
  const float* text = (const float*)d_in[4];
  const float* lsc  = (const float*)d_in[5];
  float* out = (float*)d_out;

  const int B = 16384, D = 1024, R = 256, NTP = 1536;

  char* p = (char*)d_ws;
  auto carve = [&](size_t bytes) {
    char* r = p;
    p += (bytes + 255) & ~(size_t)255;
    return r;
  };
  int*   meta  = (int*)carve(64);
  int*   bhist = (int*)carve(64 * 3 * 4);
  int*   boff  = (int*)carve(64 * 3 * 4);
  int*   perm  = (int*)carve((size_t)B * 4);
  int*   iperm = (int*)carve((size_t)B * 4);
  float* ssp   = (float*)carve((size_t)8 * B * 4);
  bf16*  Xbc   = (bf16*)carve((size_t)B * D * 2);
  bf16*  W1T   = (bf16*)carve((size_t)3 * R * D * 2);
  bf16*  W2T   = (bf16*)carve((size_t)3 * D * R * 2);
  bf16*  Tb    = (bf16*)carve((size_t)NTP * D * 2);
  bf16*  H     = (bf16*)carve((size_t)B * R * 2);
  bf16*  Fbc   = (bf16*)carve((size_t)B * D * 2);

  hist_k<<<B / 256, 256, 0, stream>>>(lab, bhist);
  scan_k<<<1, 256, 0, stream>>>(bhist, boff, meta);
  scatter2_k<<<B / 256, 256, 0, stream>>>(lab, boff, perm, iperm);

  prep_k<<<384 + 2048, 256, 0, stream>>>(x, text, W1, W2, iperm, Xbc, Tb, W1T, W2T);

  // GEMM1: H = relu(Xbc @ W1T[dom]^T), BK=64 — 768 blocks
  gemm_bt<0, 2, 64><<<768, 256, 0, stream>>>(
      Xbc, W1T, H, meta, R, D, R, R, nullptr, nullptr);
  // GEMM2: Fbc = 0.2*relu(H @ W2T^T) + 0.8*Xbc, BK=64 — 3072 blocks
  gemm_bt<1, 8, 64><<<3072, 256, 0, stream>>>(
      H, W2T, Fbc, meta, D, R, D, D, Xbc, ssp);
  // GEMM3: out[perm[row]] = exp(ls) * rinv[row] * (Fbc @ Tb^T) — 256x192 8-wave 4-phase
  gemm3_8ph<<<512, 512, 114688, stream>>>(Fbc, Tb, out, lsc, ssp, perm);
}

// Round 16
// 150.796 us; speedup vs baseline: 1.0436x; 1.0436x over previous
//
#include <hip/hip_runtime.h>
#include <hip/hip_bf16.h>
#include <math.h>

using bf16 = __hip_bfloat16;
typedef __attribute__((ext_vector_type(8))) short bf16x8;
typedef __attribute__((ext_vector_type(4))) float f32x4;
typedef __attribute__((ext_vector_type(4))) unsigned short us4;

#define GAS __attribute__((address_space(1)))
#define LAS __attribute__((address_space(3)))

__device__ __forceinline__ void gload_lds16(const bf16* g, bf16* lds) {
  __builtin_amdgcn_global_load_lds((const GAS void*)g, (LAS void*)lds, 16, 0, 0);
}
__device__ __forceinline__ float b2f(unsigned short u) {
  union { unsigned short s; bf16 b; } x; x.s = u; return __bfloat162float(x.b);
}

// ---------------- compaction (atomic-free, stable => deterministic) ----------------
__global__ __launch_bounds__(256) void hist_k(const int* __restrict__ lab,
                                              int* __restrict__ blockHist) {
  const int blk = blockIdx.x, t = threadIdx.x;
  const int lane = t & 63, w = t >> 6;
  const int d = lab[blk * 256 + t];
  __shared__ int wc[4][3];
#pragma unroll
  for (int dd = 0; dd < 3; ++dd) {
    unsigned long long m = __ballot(d == dd);
    if (lane == 0) wc[w][dd] = __popcll(m);
  }
  __syncthreads();
  if (t < 3) blockHist[blk * 3 + t] = wc[0][t] + wc[1][t] + wc[2][t] + wc[3][t];
}

// scatter with INLINE scan (scan_k merged): each block redundantly scans the 64x3
// histogram in LDS; block 0 also writes meta. Stable rank => deterministic perm/iperm.
__global__ __launch_bounds__(256) void scatter2_k(const int* __restrict__ lab,
                                                  const int* __restrict__ blockHist,
                                                  int* __restrict__ meta,
                                                  int* __restrict__ perm,
                                                  int* __restrict__ iperm) {
  const int blk = blockIdx.x, t = threadIdx.x;
  const int lane = t & 63, w = t >> 6;
  __shared__ int h[64][3];
  __shared__ int tot[3], pres[3];
  __shared__ int wc[4][3];
  if (t < 192) h[t / 3][t % 3] = blockHist[t];
  __syncthreads();
  if (t < 3) {
    int pre = 0, s = 0;
    for (int b = 0; b < 64; ++b) {
      if (b == blk) pre = s;
      s += h[b][t];
    }
    tot[t] = s;
    pres[t] = pre;
  }
  __syncthreads();
  if (blk == 0 && t == 0) {
    meta[0] = tot[0]; meta[1] = tot[1]; meta[2] = tot[2];
    meta[4] = 0; meta[5] = tot[0]; meta[6] = tot[0] + tot[1];
  }
  const int i = blk * 256 + t;
  const int d = lab[i];
  unsigned long long mymask = 0;
#pragma unroll
  for (int dd = 0; dd < 3; ++dd) {
    unsigned long long m = __ballot(d == dd);
    if (lane == 0) wc[w][dd] = __popcll(m);
    if (dd == d) mymask = m;
  }
  __syncthreads();
  int woff = 0;
  for (int ww = 0; ww < w; ++ww) woff += wc[ww][d];
  const int dbase = (d == 0) ? 0 : (d == 1 ? tot[0] : tot[0] + tot[1]);
  const unsigned long long lt = ((unsigned long long)1 << lane) - 1;
  const int rank = dbase + pres[d] + woff + __popcll(mymask & lt);
  perm[rank] = i;
  iperm[i] = rank;
}

// ------- merged prep: blocks 0..383 = LDS-tiled W1/W2 transpose+cvt; rest = cvt -------
__global__ __launch_bounds__(256) void prep_k(const float* __restrict__ x,
                                              const float* __restrict__ txt,
                                              const float* __restrict__ W1,
                                              const float* __restrict__ W2,
                                              const int* __restrict__ iperm,
                                              bf16* __restrict__ Xbc,
                                              bf16* __restrict__ Tb,
                                              bf16* __restrict__ W1T,
                                              bf16* __restrict__ W2T) {
  __shared__ float s[64][65];
  if (blockIdx.x < 384) {
    int b = blockIdx.x;
    const float* W; bf16* WT; int R, C;
    if (b < 192) { W = W1; WT = W1T; R = 1024; C = 256; }
    else         { b -= 192; W = W2; WT = W2T; R = 256; C = 1024; }
    const int d = b / 64, tb = b % 64;
    const int tilesPerRow = C / 64;
    const int r0 = (tb / tilesPerRow) * 64;
    const int c0 = (tb % tilesPerRow) * 64;
    const float* Wd = W + (size_t)d * R * C;
    bf16* WTd = WT + (size_t)d * R * C;
    const int tx = threadIdx.x & 63, ty = threadIdx.x >> 6;
#pragma unroll
    for (int i = 0; i < 16; ++i)
      s[ty + i * 4][tx] = Wd[(size_t)(r0 + ty + i * 4) * C + c0 + tx];
    __syncthreads();
#pragma unroll
    for (int i = 0; i < 16; ++i)
      WTd[(size_t)(c0 + ty + i * 4) * R + r0 + tx] = __float2bfloat16(s[tx][ty + i * 4]);
    return;
  }
  const int nx = 16384 * 1024 / 4;
  const int ntext = 1536 * 1024;
  const int total = nx + ntext;
  for (int i = (blockIdx.x - 384) * 256 + threadIdx.x; i < total; i += 2048 * 256) {
    if (i < nx) {
      const int row = i >> 8, c4 = i & 255;
      float4 v = ((const float4*)x)[i];
      bf16 t[4] = {__float2bfloat16(v.x), __float2bfloat16(v.y),
                   __float2bfloat16(v.z), __float2bfloat16(v.w)};
      ((us4*)Xbc)[(size_t)iperm[row] * 256 + c4] = *(const us4*)t;
    } else {
      int jj = i - nx;
      Tb[jj] = (jj < 1380 * 1024) ? __float2bfloat16(txt[jj]) : __float2bfloat16(0.f);
    }
  }
}

// -------- 128^2 2-phase GEMM for GEMM1/GEMM2 — dense compacted rows, BK templated --------
template <int EPI, int NBLK, int BK>
__global__ __launch_bounds__(256) void gemm_bt(
    const bf16* __restrict__ A, const bf16* __restrict__ BT, bf16* __restrict__ Cv,
    const int* __restrict__ meta, int N, int K, int ldc, int Nvalid,
    const bf16* __restrict__ xb, float* __restrict__ ssp) {
  const int bid = blockIdx.x;
  const int xcd = bid & 7;
  const int seq = bid >> 3;
  const int nblkidx = seq % NBLK;
  const int dm = xcd + 8 * (seq / NBLK);
  const int dom = dm >> 7;
  const int mblk = dm & 127;

  const int cnt = meta[dom];
  const int base = meta[4 + dom];
  BT += (size_t)dom * N * K;

  const int m0 = mblk * 128;
  if (m0 >= cnt) return;
  const int n0 = nblkidx * 128;

  constexpr int CH = BK / 8;
  __shared__ bf16 sA[2][128][BK];
  __shared__ bf16 sB[2][128][BK];

  const int tid = threadIdx.x;
  const int wid = tid >> 6;
  const int lane = tid & 63;
  const int fr = lane & 15;
  const int fq = lane >> 4;

  auto stage = [&](int buf, int kt) {
    const int koff = kt * BK;
#pragma unroll
    for (int L = 0; L < CH / 2; ++L) {
      const int idx = L * 256 + tid;
      const int r = idx / CH, c = idx % CH;
      int ar = m0 + r; if (ar > cnt - 1) ar = cnt - 1;
      gload_lds16(A + (size_t)(base + ar) * K + koff + ((c ^ (r & (CH - 1))) << 3),
                  &sA[buf][0][0] + ((idx & ~63) << 3));
    }
#pragma unroll
    for (int L = 0; L < CH / 2; ++L) {
      const int idx = L * 256 + tid;
      const int r = idx / CH, c = idx % CH;
      gload_lds16(BT + (size_t)(n0 + r) * K + koff + ((c ^ (r & (CH - 1))) << 3),
                  &sB[buf][0][0] + ((idx & ~63) << 3));
    }
  };

  f32x4 acc[4][4];
#pragma unroll
  for (int m = 0; m < 4; ++m)
#pragma unroll
    for (int n = 0; n < 4; ++n) acc[m][n] = (f32x4){0.f, 0.f, 0.f, 0.f};

  const int nk = K / BK;
  stage(0, 0);
  __syncthreads();
  const int wr = wid >> 1, wc = wid & 1;
  for (int kt = 0; kt < nk; ++kt) {
    const int cur = kt & 1;
    if (kt + 1 < nk) stage(cur ^ 1, kt + 1);
#pragma unroll
    for (int kk = 0; kk < BK / 32; ++kk) {
      const int rchunk = (((kk << 2) + fq) ^ (fr & (CH - 1))) << 3;
      bf16x8 af[4], bfr[4];
#pragma unroll
      for (int m = 0; m < 4; ++m)
        af[m] = *(const bf16x8*)&sA[cur][wr * 64 + m * 16 + fr][0 + rchunk];
#pragma unroll
      for (int n = 0; n < 4; ++n)
        bfr[n] = *(const bf16x8*)&sB[cur][wc * 64 + n * 16 + fr][0 + rchunk];
#pragma unroll
      for (int m = 0; m < 4; ++m)
#pragma unroll
        for (int n = 0; n < 4; ++n)
          acc[m][n] = __builtin_amdgcn_mfma_f32_16x16x32_bf16(af[m], bfr[n], acc[m][n], 0, 0, 0);
    }
    __syncthreads();
  }

  if (EPI == 0) {
#pragma unroll
    for (int m = 0; m < 4; ++m) {
#pragma unroll
      for (int r = 0; r < 4; ++r) {
        const int p = m0 + wr * 64 + m * 16 + fq * 4 + r;
        if (p < cnt) {
          const size_t crow = (size_t)(base + p);
#pragma unroll
          for (int n = 0; n < 4; ++n) {
            const int col = n0 + wc * 64 + n * 16 + fr;
            if (col < Nvalid)
              Cv[crow * (size_t)ldc + col] = __float2bfloat16(fmaxf(acc[m][n][r], 0.f));
          }
        }
      }
    }
  } else {
    __shared__ float ssred[128][2];
#pragma unroll
    for (int m = 0; m < 4; ++m) {
#pragma unroll
      for (int r = 0; r < 4; ++r) {
        const int lr = wr * 64 + m * 16 + fq * 4 + r;
        const int p = m0 + lr;
        float rowss = 0.f;
        if (p < cnt) {
          const size_t crow = (size_t)(base + p);
#pragma unroll
          for (int n = 0; n < 4; ++n) {
            const int col = n0 + wc * 64 + n * 16 + fr;
            const float g = 0.2f * fmaxf(acc[m][n][r], 0.f) +
                            0.8f * b2f(*(const unsigned short*)&xb[crow * 1024 + col]);
            Cv[crow * (size_t)ldc + col] = __float2bfloat16(g);
            rowss += g * g;
          }
        }
        rowss += __shfl_xor(rowss, 1, 16);
        rowss += __shfl_xor(rowss, 2, 16);
        rowss += __shfl_xor(rowss, 4, 16);
        rowss += __shfl_xor(rowss, 8, 16);
        if (fr == 0) ssred[lr][wc] = rowss;
      }
    }
    __syncthreads();
    if (tid < 128) {
      const int p = m0 + tid;
      if (p < cnt)
        ssp[(size_t)nblkidx * 16384 + base + p] = ssred[tid][0] + ssred[tid][1];
    }
  }
}

// ====== GEMM3: counted-vmcnt schedule at 2 blocks/CU (R13 winner, restored) ======
__global__ __launch_bounds__(256, 2) void gemm3_cnt(
    const bf16* __restrict__ A, const bf16* __restrict__ BT,
    float* __restrict__ C, const float* __restrict__ scale_ptr,
    const float* __restrict__ ssp, const int* __restrict__ perm) {
  extern __shared__ bf16 smem[];
  bf16* sA0 = smem;            // [2][128][64] = 32KB
  bf16* sB0 = smem + 16384;    // [2][192][64] = 48KB

  const int tid = threadIdx.x;
  const int lane = tid & 63, wid = tid >> 6;
  const int wr = wid >> 1, wc = wid & 1;     // 2x2; wave C = 64x96
  const int fr = lane & 15, fq = lane >> 4;

  const int bid = blockIdx.x;
  const int x = bid & 7, seq = bid >> 3;
  const int mb = x * 16 + (seq >> 3), nb = seq & 7;
  const int m0 = mb << 7, n0 = nb * 192;

  auto STAGE = [&](int t) {     // A 4 + B 6 gload/thread = 10 VMEM ops/thread/tile
    const int s = t & 1, koff = t << 6;
    bf16* da = sA0 + (s << 13);
#pragma unroll
    for (int L = 0; L < 4; ++L) {
      const int idx = (L << 8) + tid;
      const int r = idx >> 3, c = idx & 7;
      gload_lds16(A + (size_t)(m0 + r) * 1024 + koff + ((c ^ (r & 7)) << 3),
                  da + ((idx & ~63) << 3));
    }
    bf16* db = sB0 + s * 12288;
#pragma unroll
    for (int L = 0; L < 6; ++L) {
      const int idx = (L << 8) + tid;
      const int r = idx >> 3, c = idx & 7;
      gload_lds16(BT + (size_t)(n0 + r) * 1024 + koff + ((c ^ (r & 7)) << 3),
                  db + ((idx & ~63) << 3));
    }
  };
  auto LDA = [&](int s, int kk, bf16x8* dst) {
    const bf16* base = sA0 + (s << 13);
#pragma unroll
    for (int m = 0; m < 4; ++m) {
      const int row = (wr << 6) + (m << 4) + fr;
      dst[m] = *(const bf16x8*)(base + (row << 6) + ((((kk << 2) + fq) ^ (fr & 7)) << 3));
    }
  };
  auto LDB = [&](int s, int kk, bf16x8* dst) {
    const bf16* base = sB0 + s * 12288;
#pragma unroll
    for (int n = 0; n < 6; ++n) {
      const int row = wc * 96 + (n << 4) + fr;
      dst[n] = *(const bf16x8*)(base + (row << 6) + ((((kk << 2) + fq) ^ (fr & 7)) << 3));
    }
  };

  f32x4 acc[4][6];
#pragma unroll
  for (int m = 0; m < 4; ++m)
#pragma unroll
    for (int n = 0; n < 6; ++n) acc[m][n] = (f32x4){0.f, 0.f, 0.f, 0.f};

  STAGE(0); STAGE(1);
  asm volatile("s_waitcnt vmcnt(10)" ::: "memory");
  __builtin_amdgcn_s_barrier();

  const int nt = 16;
  for (int t = 0; t < nt; ++t) {
    const int s = t & 1;
    bf16x8 a0[4], a1[4], b0[6], b1[6];
    LDA(s, 0, a0); LDB(s, 0, b0);
    LDA(s, 1, a1); LDB(s, 1, b1);
    asm volatile("s_waitcnt lgkmcnt(0)" ::: "memory");
    __builtin_amdgcn_sched_barrier(0);
    __builtin_amdgcn_s_barrier();
    __builtin_amdgcn_sched_barrier(0);
    if (t + 2 < nt) STAGE(t + 2);
    __builtin_amdgcn_s_setprio(1);
#pragma unroll
    for (int m = 0; m < 4; ++m)
#pragma unroll
      for (int n = 0; n < 6; ++n)
        acc[m][n] = __builtin_amdgcn_mfma_f32_16x16x32_bf16(a0[m], b0[n], acc[m][n], 0, 0, 0);
#pragma unroll
    for (int m = 0; m < 4; ++m)
#pragma unroll
      for (int n = 0; n < 6; ++n)
        acc[m][n] = __builtin_amdgcn_mfma_f32_16x16x32_bf16(a1[m], b1[n], acc[m][n], 0, 0, 0);
    __builtin_amdgcn_s_setprio(0);
    if (t + 2 < nt) {
      asm volatile("s_waitcnt vmcnt(10)" ::: "memory");
    } else if (t + 1 < nt) {
      asm volatile("s_waitcnt vmcnt(0)" ::: "memory");
    }
    __builtin_amdgcn_sched_barrier(0);
    __builtin_amdgcn_s_barrier();
    __builtin_amdgcn_sched_barrier(0);
  }

  float* rlds = (float*)smem;
  int*   plds = (int*)((char*)smem + 512);
  if (tid < 128) {
    float s = 0.f;
#pragma unroll
    for (int b = 0; b < 8; ++b) s += ssp[b * 16384 + m0 + tid];
    rlds[tid] = rsqrtf(s);
    plds[tid] = perm[m0 + tid];
  }
  __syncthreads();

  const float sc = expf(*scale_ptr);
#pragma unroll
  for (int m = 0; m < 4; ++m) {
    const int lrow = (wr << 6) + (m << 4) + (fq << 2);
#pragma unroll
    for (int r = 0; r < 4; ++r) {
      const float rv = sc * rlds[lrow + r];
      const size_t orow = (size_t)plds[lrow + r];
#pragma unroll
      for (int n = 0; n < 6; ++n) {
        const int gcol = n0 + wc * 96 + (n << 4) + fr;
        if (gcol < 1380) C[orow * 1380 + gcol] = acc[m][n][r] * rv;
      }
    }
  }
}

extern "C" void kernel_launch(void* const* d_in, const int* in_sizes, int n_in,
                              void* d_out, int out_size, void* d_ws, size_t ws_size,
                              hipStream_t stream) {
  (void)in_sizes; (void)n_in; (void)out_size; (void)ws_size;
  const float* x    = (const float*)d_in[0];
  const int*   lab  = (const int*)d_in[1];
  const float* W1   = (const float*)d_in[2];
  const float* W2   = (const float*)d_in[3];
  const float* text = (const float*)d_in[4];
  const float* lsc  = (const float*)d_in[5];
  float* out = (float*)d_out;

  const int B = 16384, D = 1024, R = 256, NTP = 1536;

  char* p = (char*)d_ws;
  auto carve = [&](size_t bytes) {
    char* r = p;
    p += (bytes + 255) & ~(size_t)255;
    return r;
  };
  int*   meta  = (int*)carve(64);
  int*   bhist = (int*)carve(64 * 3 * 4);
  int*   perm  = (int*)carve((size_t)B * 4);
  int*   iperm = (int*)carve((size_t)B * 4);
  float* ssp   = (float*)carve((size_t)8 * B * 4);
  bf16*  Xbc   = (bf16*)carve((size_t)B * D * 2);
  bf16*  W1T   = (bf16*)carve((size_t)3 * R * D * 2);
  bf16*  W2T   = (bf16*)carve((size_t)3 * D * R * 2);
  bf16*  Tb    = (bf16*)carve((size_t)NTP * D * 2);
  bf16*  H     = (bf16*)carve((size_t)B * R * 2);
  bf16*  Fbc   = (bf16*)carve((size_t)B * D * 2);

  hist_k<<<B / 256, 256, 0, stream>>>(lab, bhist);
  scatter2_k<<<B / 256, 256, 0, stream>>>(lab, bhist, meta, perm, iperm);

  prep_k<<<384 + 2048, 256, 0, stream>>>(x, text, W1, W2, iperm, Xbc, Tb, W1T, W2T);

  // GEMM1: H = relu(Xbc @ W1T[dom]^T), BK=64 — 768 blocks
  gemm_bt<0, 2, 64><<<768, 256, 0, stream>>>(
      Xbc, W1T, H, meta, R, D, R, R, nullptr, nullptr);
  // GEMM2: Fbc = 0.2*relu(H @ W2T^T) + 0.8*Xbc, BK=64 — 3072 blocks
  gemm_bt<1, 8, 64><<<3072, 256, 0, stream>>>(
      H, W2T, Fbc, meta, D, R, D, D, Xbc, ssp);
  // GEMM3: out[perm[row]] = exp(ls) * rinv[row] * (Fbc @ Tb^T) — counted-vmcnt, 2 blk/CU
  gemm3_cnt<<<1024, 256, 81920, stream>>>(Fbc, Tb, out, lsc, ssp, perm);
}